// Round 20
// baseline (381.772 us; speedup 1.0000x reference)
//
#include <hip/hip_runtime.h>
#include <math.h>

#define Bb    32
#define Nn    4096
#define HISTC 16
#define PREDC 8
#define TTC   24
#define EC    65536
#define BN    (Bb*Nn)          // 131072
#define NSL   768              // 512 hist + 256 pred slices

typedef float f32x2 __attribute__((ext_vector_type(2)));
typedef float f32x4 __attribute__((ext_vector_type(4)));
typedef __fp16 f16x8 __attribute__((ext_vector_type(8)));
typedef __fp16 fp16v2 __attribute__((ext_vector_type(2)));

__device__ __forceinline__ float sigm_f(float x){
  return __builtin_amdgcn_rcpf(1.f + __expf(-x));
}
__device__ __forceinline__ float tanh_f(float x){
  return fmaf(-2.f, __builtin_amdgcn_rcpf(1.f + __expf(2.f*x)), 1.f);
}
__device__ __forceinline__ unsigned pk2(float a, float b){
  fp16v2 v = __builtin_amdgcn_cvt_pkrtz(a, b);
  return __builtin_bit_cast(unsigned, v);
}
__device__ __forceinline__ void unpk2(unsigned u, float& a, float& b){
  fp16v2 v = __builtin_bit_cast(fp16v2, u);
  a = (float)v.x; b = (float)v.y;
}
__device__ __forceinline__ f32x4 mfma16(uint4 a, uint4 b, f32x4 c){
  return __builtin_amdgcn_mfma_f32_16x16x32_f16(
      __builtin_bit_cast(f16x8, a), __builtin_bit_cast(f16x8, b), c, 0, 0, 0);
}

// ---------------- CSR build ----------------
__global__ void k_deg(const int* __restrict__ ei, int* deg, int* cnt){
  int e = blockIdx.x*blockDim.x + threadIdx.x;
  if (e < EC){ atomicAdd(&deg[ei[e]],1); atomicAdd(&cnt[ei[EC+e]],1); }
}
__global__ void k_scan(const int* __restrict__ cnt, int* ptr){
  __shared__ int sd[1024];
  int t = threadIdx.x;
  int c0=cnt[4*t], c1=cnt[4*t+1], c2=cnt[4*t+2], c3=cnt[4*t+3];
  int s = c0+c1+c2+c3;
  sd[t] = s; __syncthreads();
  for (int off=1; off<1024; off<<=1){
    int v = (t>=off) ? sd[t-off] : 0;
    __syncthreads();
    sd[t] += v;
    __syncthreads();
  }
  int excl = sd[t]-s;
  ptr[4*t]=excl; ptr[4*t+1]=excl+c0; ptr[4*t+2]=excl+c0+c1; ptr[4*t+3]=excl+c0+c1+c2;
  if (t==1023) ptr[4096]=sd[1023];
}
// merged: block 0 -> dis; blocks 1..8 -> weight-fragment build (r17 table)
__global__ void k_misc(const int* __restrict__ deg, float* __restrict__ dis,
                       const float* __restrict__ x2hw, const float* __restrict__ h2hw,
                       const float* __restrict__ x2hb, const float* __restrict__ h2hb,
                       _Float16* __restrict__ wfrag){
  if (blockIdx.x == 0){
    #pragma unroll
    for (int k=0;k<4;++k){
      int n = threadIdx.x + k*1024;
      dis[n] = deg[n] > 0 ? rsqrtf((float)deg[n]) : 0.f;
    }
  } else {
    int i = (blockIdx.x-1)*1024 + threadIdx.x;     // 8192 total
    int f = i >> 9, lane = (i >> 3) & 63, j = i & 7;
    int kt = f >> 3, ct = f & 7;
    int k = kt*32 + (lane>>4)*8 + j;
    int col = ct*16 + (lane&15);
    float v;
    if (k < 12)       v = x2hw[k*128 + col];
    else if (k == 12) v = x2hb[col] + h2hb[col];
    else if (k < 32)  v = 0.f;
    else              v = h2hw[(k-32)*128 + col];
    wfrag[f*512 + lane*8 + j] = (_Float16)v;
  }
}
__global__ void k_fill(const int* __restrict__ ei, const float* __restrict__ dis,
                       const int* __restrict__ ptr, int* fillc, int2* __restrict__ epack){
  int e = blockIdx.x*blockDim.x + threadIdx.x;
  if (e < EC){
    int s = ei[e], d = ei[EC+e];
    int pos = ptr[d] + atomicAdd(&fillc[d],1);
    epack[pos] = make_int2(s, __float_as_int(-dis[s]*dis[d]));
  }
}

// ---------------- fused z + transpose: writes zT[n][slice] directly ----------
__global__ __launch_bounds__(256)
void k_zt(const float* __restrict__ pm25, const float* __restrict__ feat,
          const float* __restrict__ cw, f32x2* __restrict__ zT){
  __shared__ f32x2 tile[64][65];
  int nb = blockIdx.x & 63, sb = blockIdx.x >> 6;   // sb 0..11
  int n0 = nb*64, s0 = sb*64;
  int tid = threadIdx.x;
  #pragma unroll
  for (int k=0;k<16;++k){
    int i = tid + k*256;
    int r = i >> 6, c = i & 63;                     // r = slice off, c = node off
    int slice = s0 + r, n = n0 + c;
    int b = slice & 31;
    int t;
    float z0, z1;
    if (slice < 512){
      t = (slice >> 5) & 15;
      float x0 = pm25[((size_t)(b*HISTC + t))*Nn + n];
      z0 = x0*cw[20]; z1 = x0*cw[21];
    } else {
      t = HISTC + ((slice - 512) >> 5);
      z0 = 0.f; z1 = 0.f;
    }
    const float* fp = feat + ((size_t)(b*TTC + t)*Nn + n)*9;
    #pragma unroll
    for (int f=0;f<9;++f){
      float v = fp[f];
      z0 = fmaf(v, cw[20+(f+1)*2+0], z0); z1 = fmaf(v, cw[20+(f+1)*2+1], z1);
    }
    tile[r][c] = (f32x2){z0, z1};
  }
  __syncthreads();
  #pragma unroll
  for (int k=0;k<16;++k){
    int i = tid + k*256;
    int r = i >> 6, c = i & 63;                     // r = node off, c = slice off
    zT[(size_t)(n0 + r)*NSL + s0 + c] = tile[c][r];
  }
}

// ---------------- generic tiled transpose of f32x2 matrix [R][C] -> [C][R] ----
__global__ __launch_bounds__(256)
void k_tr(const f32x2* __restrict__ in, f32x2* __restrict__ out, int R, int C){
  __shared__ f32x2 tile[64][65];
  int tilesR = R >> 6;
  int br = blockIdx.x % tilesR, bc = blockIdx.x / tilesR;
  int r0 = br << 6, c0 = bc << 6;
  for (int i=threadIdx.x; i<4096; i+=256){
    int r = i>>6, c = i&63;
    tile[r][c] = in[(size_t)(r0+r)*C + c0+c];
  }
  __syncthreads();
  for (int i=threadIdx.x; i<4096; i+=256){
    int r = i>>6, c = i&63;
    out[(size_t)(c0+r)*R + r0+c] = tile[c][r];
  }
}

// ---------------- column-split dense agg: 6 passes of 64 float4 cols ----------
__global__ __launch_bounds__(64)
void k_aggc(const int* __restrict__ ptr, const int2* __restrict__ epack,
            const float4* __restrict__ zT, float4* __restrict__ aggT){
  int n  = blockIdx.x & (Nn-1);
  int cb = blockIdx.x >> 12;
  int col = cb*64 + threadIdx.x;              // float4 index in 384-wide row
  int p0 = ptr[n], p1 = ptr[n+1];
  f32x4 acc = {0.f,0.f,0.f,0.f};
  int i = p0;
  for (; i+1 < p1; i += 2){
    int2 e0 = epack[i], e1 = epack[i+1];
    float w0 = __int_as_float(e0.y), w1 = __int_as_float(e1.y);
    float4 z0 = zT[(size_t)e0.x*384 + col];
    float4 z1 = zT[(size_t)e1.x*384 + col];
    acc.x = fmaf(w0, z0.x, acc.x); acc.y = fmaf(w0, z0.y, acc.y);
    acc.z = fmaf(w0, z0.z, acc.z); acc.w = fmaf(w0, z0.w, acc.w);
    acc.x = fmaf(w1, z1.x, acc.x); acc.y = fmaf(w1, z1.y, acc.y);
    acc.z = fmaf(w1, z1.z, acc.z); acc.w = fmaf(w1, z1.w, acc.w);
  }
  if (i < p1){
    int2 e = epack[i];
    float w = __int_as_float(e.y);
    float4 z = zT[(size_t)e.x*384 + col];
    acc.x = fmaf(w, z.x, acc.x); acc.y = fmaf(w, z.y, acc.y);
    acc.z = fmaf(w, z.z, acc.z); acc.w = fmaf(w, z.w, acc.w);
  }
  aggT[(size_t)n*384 + col] = make_float4(acc.x, acc.y, acc.z, acc.w);
}

// ---------------- MFMA LSTM pointwise helper (proven) ----------------
#define POINTWISE(r)                                                            \
  c0[r] = fmaf(sigm_f(acc[0][r]), tanh_f(acc[4][r]), sigm_f(acc[2][r])*c0[r]);  \
  h0[r] = sigm_f(acc[6][r])*tanh_f(c0[r]);                                      \
  c1[r] = fmaf(sigm_f(acc[1][r]), tanh_f(acc[5][r]), sigm_f(acc[3][r])*c1[r]);  \
  h1[r] = sigm_f(acc[7][r])*tanh_f(c1[r]);

// ---------------- persistent history LSTM: 2 INTERLEAVED tiles per wave -------
__global__ __launch_bounds__(256,1)
void k_hist(const float* __restrict__ pm25, const float* __restrict__ feat,
            const f32x2* __restrict__ aggH,
            const float* __restrict__ cw, const float* __restrict__ cb,
            const uint4* __restrict__ wfrag,
            const float* __restrict__ fcw, const float* __restrict__ fcb,
            uint4* __restrict__ hfragO, uint4* __restrict__ cO,
            float* __restrict__ xn0){
  __shared__ __align__(16) uint4 wl[1024];          // 16 KB weight fragments
  __shared__ __align__(16) _Float16 hl[4][2][16][40];
  int tid = threadIdx.x;
  int lane = tid & 63, w = tid >> 6;
  for (int i = tid; i < 1024; i += 256) wl[i] = wfrag[i];
  int gwA = (blockIdx.x*4 + w)*2;                   // even tile
  int gwB = gwA + 1;                                // odd tile (same b: 256 tiles/b)
  int r0A = gwA*16, r0B = gwB*16;
  int b = r0A >> 12;
  int n0A = r0A & (Nn-1);
  int l15 = lane & 15, g4 = lane >> 4;
  int nrowA = n0A + l15, nrowB = nrowA + 16;
  const float* pbA = pm25 + (size_t)b*HISTC*Nn + nrowA;
  const float* pbB = pbA + 16;
  const float* fbA = feat + ((size_t)b*TTC*Nn + nrowA)*9;
  const float* fbB = fbA + 16*9;

  float fw0 = fcw[l15], fw1 = fcw[l15+16];
  const f32x4 zacc = {0.f,0.f,0.f,0.f};

  uint4 ahA = make_uint4(0,0,0,0), ahB = make_uint4(0,0,0,0);
  float c0A[4]={0,0,0,0}, c1A[4]={0,0,0,0};
  float c0B[4]={0,0,0,0}, c1B[4]={0,0,0,0};
  float h0A[4], h1A[4], h0B[4], h1B[4];
  __syncthreads();                                  // wl ready

  #pragma unroll 1
  for (int t=0; t<HISTC; ++t){
    int wofs = lane;
    asm volatile("" : "+v"(wofs));                  // opaque: prevent hoisting wl reads
    const float* fbtA = fbA + (size_t)t*Nn*9;
    const float* fbtB = fbB + (size_t)t*Nn*9;
    // ----- inputs A and B (independent load chains) -----
    float xvA[9], xvB[9];
    float a0A=0.f, a1A=0.f, x0A=0.f, a0B=0.f, a1B=0.f, x0B=0.f;
    if (g4 == 0){
      x0A = pbA[(size_t)t*Nn];  x0B = pbB[(size_t)t*Nn];
      #pragma unroll
      for (int f=0;f<7;++f){ xvA[f] = fbtA[f]; xvB[f] = fbtB[f]; }
      a0A = x0A*cw[0]; a1A = x0A*cw[1];
      a0B = x0B*cw[0]; a1B = x0B*cw[1];
      #pragma unroll
      for (int f=0;f<7;++f){
        a0A += xvA[f]*cw[(f+1)*2]; a1A += xvA[f]*cw[(f+1)*2+1];
        a0B += xvB[f]*cw[(f+1)*2]; a1B += xvB[f]*cw[(f+1)*2+1];
      }
    } else if (g4 == 1){
      xvA[7] = fbtA[7]; xvA[8] = fbtA[8];
      xvB[7] = fbtB[7]; xvB[8] = fbtB[8];
      a0A = cb[0] + xvA[7]*cw[16] + xvA[8]*cw[18];
      a1A = cb[1] + xvA[7]*cw[17] + xvA[8]*cw[19];
      a0B = cb[0] + xvB[7]*cw[16] + xvB[8]*cw[18];
      a1B = cb[1] + xvB[7]*cw[17] + xvB[8]*cw[19];
    } else if (g4 == 2){
      f32x2 agA = aggH[((size_t)(t*Bb + b))*Nn + nrowA];
      f32x2 agB = aggH[((size_t)(t*Bb + b))*Nn + nrowB];
      a0A = agA.x; a1A = agA.y; a0B = agB.x; a1B = agB.y;
    }
    a0A += __shfl_xor(a0A, 16); a0A += __shfl_xor(a0A, 32);
    a1A += __shfl_xor(a1A, 16); a1A += __shfl_xor(a1A, 32);
    a0B += __shfl_xor(a0B, 16); a0B += __shfl_xor(a0B, 32);
    a1B += __shfl_xor(a1B, 16); a1B += __shfl_xor(a1B, 32);
    float xg0A = sigm_f(a0A), xg1A = sigm_f(a1A);
    float xg0B = sigm_f(a0B), xg1B = sigm_f(a1B);

    uint4 axA, axB;
    if (g4 == 0){
      axA.x = pk2(x0A, xvA[0]);    axA.y = pk2(xvA[1], xvA[2]);
      axA.z = pk2(xvA[3], xvA[4]); axA.w = pk2(xvA[5], xvA[6]);
      axB.x = pk2(x0B, xvB[0]);    axB.y = pk2(xvB[1], xvB[2]);
      axB.z = pk2(xvB[3], xvB[4]); axB.w = pk2(xvB[5], xvB[6]);
    } else if (g4 == 1){
      axA.x = pk2(xvA[7], xvA[8]); axA.y = pk2(xg0A, xg1A);
      axA.z = pk2(1.f, 0.f);       axA.w = 0u;
      axB.x = pk2(xvB[7], xvB[8]); axB.y = pk2(xg0B, xg1B);
      axB.z = pk2(1.f, 0.f);       axB.w = 0u;
    } else {
      axA = make_uint4(0,0,0,0);   axB = make_uint4(0,0,0,0);
    }

    // ----- dual MFMA (independent chains interleave) -----
    f32x4 accA[8], accB[8];
    #pragma unroll
    for (int ct=0; ct<8; ++ct){
      uint4 b0 = wl[wofs + ct*64];
      uint4 b1 = wl[wofs + 512 + ct*64];
      accA[ct] = mfma16(axA, b0, zacc);
      accB[ct] = mfma16(axB, b0, zacc);
      accA[ct] = mfma16(ahA, b1, accA[ct]);
      accB[ct] = mfma16(ahB, b1, accB[ct]);
    }

    // ----- dual pointwise -----
    {
      f32x4 (&acc)[8] = accA;
      float (&c0)[4] = c0A; float (&c1)[4] = c1A;
      float (&h0)[4] = h0A; float (&h1)[4] = h1A;
      POINTWISE(0) POINTWISE(1) POINTWISE(2) POINTWISE(3)
    }
    {
      f32x4 (&acc)[8] = accB;
      float (&c0)[4] = c0B; float (&c1)[4] = c1B;
      float (&h0)[4] = h0B; float (&h1)[4] = h1B;
      POINTWISE(0) POINTWISE(1) POINTWISE(2) POINTWISE(3)
    }

    // ----- dual h exchange -----
    #pragma unroll
    for (int r=0;r<4;++r){
      hl[w][0][g4*4+r][l15]    = (_Float16)h0A[r];
      hl[w][0][g4*4+r][l15+16] = (_Float16)h1A[r];
      hl[w][1][g4*4+r][l15]    = (_Float16)h0B[r];
      hl[w][1][g4*4+r][l15+16] = (_Float16)h1B[r];
    }
    asm volatile("s_waitcnt lgkmcnt(0)" ::: "memory");
    ahA = *(const uint4*)&hl[w][0][l15][g4*8];
    ahB = *(const uint4*)&hl[w][1][l15][g4*8];
  }

  hfragO[(size_t)gwA*64 + lane] = ahA;
  hfragO[(size_t)gwB*64 + lane] = ahB;
  {
    uint4 cp;
    cp.x = pk2(c0A[0], c0A[1]); cp.y = pk2(c0A[2], c0A[3]);
    cp.z = pk2(c1A[0], c1A[1]); cp.w = pk2(c1A[2], c1A[3]);
    cO[(size_t)gwA*64 + lane] = cp;
    cp.x = pk2(c0B[0], c0B[1]); cp.y = pk2(c0B[2], c0B[3]);
    cp.z = pk2(c1B[0], c1B[1]); cp.w = pk2(c1B[2], c1B[3]);
    cO[(size_t)gwB*64 + lane] = cp;
  }
  #pragma unroll
  for (int r=0;r<4;++r){
    float pA = fmaf(h0A[r], fw0, h1A[r]*fw1);
    pA += __shfl_xor(pA, 1, 16); pA += __shfl_xor(pA, 2, 16);
    pA += __shfl_xor(pA, 4, 16); pA += __shfl_xor(pA, 8, 16);
    float pB = fmaf(h0B[r], fw0, h1B[r]*fw1);
    pB += __shfl_xor(pB, 1, 16); pB += __shfl_xor(pB, 2, 16);
    pB += __shfl_xor(pB, 4, 16); pB += __shfl_xor(pB, 8, 16);
    if (l15 == 0){
      xn0[r0A + g4*4 + r] = pA + fcb[0];
      xn0[r0B + g4*4 + r] = pB + fcb[0];
    }
  }
}

// ---------------- pred step (round-17 proven) ----------------
__global__ __launch_bounds__(256,1)
void k_pred_cell(const float* __restrict__ feat,
                 const float* __restrict__ xnI, float* __restrict__ xnO,
                 const f32x2* __restrict__ aggzf,     // pre-offset by (512+tp*32)*Nn
                 const int* __restrict__ ptr, const int2* __restrict__ epack,
                 const float* __restrict__ cw, const float* __restrict__ cb,
                 const uint4* __restrict__ wfrag,
                 const float* __restrict__ fcw, const float* __restrict__ fcb,
                 uint4* __restrict__ hfrag, uint4* __restrict__ cS,
                 float* __restrict__ out, int t){
  __shared__ __align__(16) uint4 wl[1024];
  __shared__ __align__(16) _Float16 hl[4][16][40];
  int tid = threadIdx.x;
  int lane = tid & 63, w = tid >> 6;
  for (int i = tid; i < 1024; i += 256) wl[i] = wfrag[i];
  int gw = blockIdx.x*4 + w;
  int r0 = gw*16;
  int b = r0 >> 12, n0 = r0 & (Nn-1);
  int l15 = lane & 15, g4 = lane >> 4;
  int nrow = n0 + l15;

  float fw0 = fcw[l15], fw1 = fcw[l15+16];

  uint4 ah = hfrag[(size_t)gw*64 + lane];
  float c0[4], c1[4];
  {
    uint4 cv = cS[(size_t)gw*64 + lane];
    unpk2(cv.x, c0[0], c0[1]); unpk2(cv.y, c0[2], c0[3]);
    unpk2(cv.z, c1[0], c1[1]); unpk2(cv.w, c1[2], c1[3]);
  }
  float h0[4], h1[4];
  const f32x4 zacc = {0.f,0.f,0.f,0.f};

  const float* fbt = feat + ((size_t)(b*TTC + t)*Nn + nrow)*9;
  const float* xb = xnI + (size_t)b*Nn;
  float xv[9]; float a0 = 0.f, a1 = 0.f; float x0 = 0.f;
  if (g4 == 0){
    x0 = xb[nrow];
    #pragma unroll
    for (int f=0;f<7;++f) xv[f] = fbt[f];
    a0 = x0*cw[0]; a1 = x0*cw[1];
    #pragma unroll
    for (int f=0;f<7;++f){ a0 += xv[f]*cw[(f+1)*2]; a1 += xv[f]*cw[(f+1)*2+1]; }
  } else if (g4 == 1){
    xv[7] = fbt[7]; xv[8] = fbt[8];
    a0 = cb[0] + xv[7]*cw[16] + xv[8]*cw[18];
    a1 = cb[1] + xv[7]*cw[17] + xv[8]*cw[19];
  } else if (g4 == 2){
    f32x2 azf = aggzf[(size_t)b*Nn + nrow];
    a0 = azf.x; a1 = azf.y;
  }
  // in-wave xn sparse gather: 4 lanes (g4) split row nrow's CSR range
  {
    int p0 = ptr[nrow], p1 = ptr[nrow+1];
    float pax = 0.f;
    for (int i = p0 + g4; i < p1; i += 4){
      int2 e = epack[i];
      pax = fmaf(__int_as_float(e.y), xb[e.x], pax);
    }
    a0 = fmaf(pax, cw[20], a0);
    a1 = fmaf(pax, cw[21], a1);
  }
  a0 += __shfl_xor(a0, 16); a0 += __shfl_xor(a0, 32);
  a1 += __shfl_xor(a1, 16); a1 += __shfl_xor(a1, 32);
  float xg0 = sigm_f(a0), xg1 = sigm_f(a1);

  uint4 ax;
  if (g4 == 0){
    ax.x = pk2(x0, xv[0]);     ax.y = pk2(xv[1], xv[2]);
    ax.z = pk2(xv[3], xv[4]);  ax.w = pk2(xv[5], xv[6]);
  } else if (g4 == 1){
    ax.x = pk2(xv[7], xv[8]);  ax.y = pk2(xg0, xg1);
    ax.z = pk2(1.f, 0.f);      ax.w = 0u;
  } else {
    ax = make_uint4(0,0,0,0);
  }

  __syncthreads();                                  // wl ready
  f32x4 acc[8];
  #pragma unroll
  for (int ct=0; ct<8; ++ct){
    uint4 b0 = wl[lane + ct*64];
    uint4 b1 = wl[lane + 512 + ct*64];
    acc[ct] = mfma16(ax, b0, zacc);
    acc[ct] = mfma16(ah, b1, acc[ct]);
  }

  POINTWISE(0) POINTWISE(1) POINTWISE(2) POINTWISE(3)

  #pragma unroll
  for (int r=0;r<4;++r){
    hl[w][g4*4+r][l15]    = (_Float16)h0[r];
    hl[w][g4*4+r][l15+16] = (_Float16)h1[r];
  }
  asm volatile("s_waitcnt lgkmcnt(0)" ::: "memory");
  ah = *(const uint4*)&hl[w][l15][g4*8];

  hfrag[(size_t)gw*64 + lane] = ah;
  {
    uint4 cp;
    cp.x = pk2(c0[0], c0[1]); cp.y = pk2(c0[2], c0[3]);
    cp.z = pk2(c1[0], c1[1]); cp.w = pk2(c1[2], c1[3]);
    cS[(size_t)gw*64 + lane] = cp;
  }
  #pragma unroll
  for (int r=0;r<4;++r){
    float p = fmaf(h0[r], fw0, h1[r]*fw1);
    p += __shfl_xor(p, 1, 16); p += __shfl_xor(p, 2, 16);
    p += __shfl_xor(p, 4, 16); p += __shfl_xor(p, 8, 16);
    if (l15 == 0){
      float rr = p + fcb[0];
      int nr = n0 + g4*4 + r;
      xnO[r0 + g4*4 + r] = rr;
      out[(size_t)b*PREDC*Nn + nr] = rr;      // out pre-offset by tp*Nn
    }
  }
}

// ---------------- host ----------------
extern "C" void kernel_launch(void* const* d_in, const int* in_sizes, int n_in,
                              void* d_out, int out_size, void* d_ws, size_t ws_size,
                              hipStream_t stream){
  const float* pm25 = (const float*)d_in[0];
  const float* feat = (const float*)d_in[1];
  const int*   ei   = (const int*)d_in[2];
  const float* cw   = (const float*)d_in[3];
  const float* cb   = (const float*)d_in[4];
  const float* x2hw = (const float*)d_in[5];
  const float* x2hb = (const float*)d_in[6];
  const float* h2hw = (const float*)d_in[7];
  const float* h2hb = (const float*)d_in[8];
  const float* fcw  = (const float*)d_in[9];
  const float* fcb  = (const float*)d_in[10];
  float* out = (float*)d_out;

  char* wsp = (char*)d_ws;
  size_t off = 0;
  auto take = [&](size_t bytes)->char*{
    char* r = wsp + off; off += (bytes + 255) & ~(size_t)255; return r;
  };
  int*      deg   = (int*)      take(Nn*4);
  int*      cnt   = (int*)      take(Nn*4);
  int*      fillc = (int*)      take(Nn*4);
  int*      ptr   = (int*)      take((Nn+1)*4);
  float*    dis   = (float*)    take(Nn*4);
  int2*     epack = (int2*)     take(EC*8);
  _Float16* wfrag = (_Float16*) take(16*512*2);
  char*     bufA  =             take((size_t)NSL*Nn*8);   // aggT -> {hfrag,cbuf}
  char*     bufB  =             take((size_t)NSL*Nn*8);   // zT   -> aggAll
  float*    xn0   = (float*)    take((size_t)BN*4);
  float*    xn1   = (float*)    take((size_t)BN*4);

  uint4*  hfrag = (uint4*)bufA;                           // reuse after agg pipeline
  uint4*  cbuf  = (uint4*)(bufA + (size_t)8388608);       // f16-packed c state

  (void)hipMemsetAsync(deg, 0, Nn*4*3, stream);   // deg,cnt,fillc adjacent

  k_deg <<<EC/256, 256, 0, stream>>>(ei, deg, cnt);
  k_scan<<<1, 1024, 0, stream>>>(cnt, ptr);
  k_misc<<<9, 1024, 0, stream>>>(deg, dis, x2hw, h2hw, x2hb, h2hb, wfrag);
  k_fill<<<EC/256, 256, 0, stream>>>(ei, dis, ptr, fillc, epack);

  // dense agg pipeline: fused z+transpose -> dense agg -> transpose back
  k_zt<<<(NSL/64)*(Nn/64), 256, 0, stream>>>(pm25, feat, cw, (f32x2*)bufB);
  k_aggc<<<6*Nn, 64, 0, stream>>>(ptr, epack, (const float4*)bufB, (float4*)bufA);
  k_tr<<<(Nn/64)*(NSL/64), 256, 0, stream>>>((const f32x2*)bufA, (f32x2*)bufB, Nn, NSL);

  const f32x2* aggAll = (const f32x2*)bufB;     // [768][4096]

  k_hist<<<BN/128, 256, 0, stream>>>(pm25, feat, aggAll, cw, cb,
                                     (const uint4*)wfrag, fcw, fcb,
                                     hfrag, cbuf, xn0);

  for (int tp = 0; tp < PREDC; ++tp){
    int t = HISTC + tp;
    const float* xi = (tp & 1) ? xn1 : xn0;
    float*       xo = (tp & 1) ? xn0 : xn1;
    k_pred_cell<<<BN/64, 256, 0, stream>>>(feat, xi, xo,
                                           aggAll + (size_t)(512 + tp*Bb)*Nn,
                                           ptr, epack, cw, cb,
                                           (const uint4*)wfrag, fcw, fcb,
                                           hfrag, cbuf, out + (size_t)tp*Nn, t);
  }
}

// Round 21
// 370.687 us; speedup vs baseline: 1.0299x; 1.0299x over previous
//
#include <hip/hip_runtime.h>
#include <math.h>

#define Bb    32
#define Nn    4096
#define HISTC 16
#define PREDC 8
#define TTC   24
#define EC    65536
#define BN    (Bb*Nn)          // 131072
#define NSL   768              // 512 hist + 256 pred slices

typedef float f32x2 __attribute__((ext_vector_type(2)));
typedef float f32x4 __attribute__((ext_vector_type(4)));
typedef __fp16 f16x8 __attribute__((ext_vector_type(8)));
typedef __fp16 fp16v2 __attribute__((ext_vector_type(2)));

__device__ __forceinline__ float sigm_f(float x){
  return __builtin_amdgcn_rcpf(1.f + __expf(-x));
}
__device__ __forceinline__ float tanh_f(float x){
  return fmaf(-2.f, __builtin_amdgcn_rcpf(1.f + __expf(2.f*x)), 1.f);
}
__device__ __forceinline__ unsigned pk2(float a, float b){
  fp16v2 v = __builtin_amdgcn_cvt_pkrtz(a, b);
  return __builtin_bit_cast(unsigned, v);
}
__device__ __forceinline__ void unpk2(unsigned u, float& a, float& b){
  fp16v2 v = __builtin_bit_cast(fp16v2, u);
  a = (float)v.x; b = (float)v.y;
}
__device__ __forceinline__ f32x4 mfma16(uint4 a, uint4 b, f32x4 c){
  return __builtin_amdgcn_mfma_f32_16x16x32_f16(
      __builtin_bit_cast(f16x8, a), __builtin_bit_cast(f16x8, b), c, 0, 0, 0);
}

// ---------------- CSR build ----------------
__global__ void k_deg(const int* __restrict__ ei, int* deg, int* cnt){
  int e = blockIdx.x*blockDim.x + threadIdx.x;
  if (e < EC){ atomicAdd(&deg[ei[e]],1); atomicAdd(&cnt[ei[EC+e]],1); }
}
__global__ void k_scan(const int* __restrict__ cnt, int* ptr){
  __shared__ int sd[1024];
  int t = threadIdx.x;
  int c0=cnt[4*t], c1=cnt[4*t+1], c2=cnt[4*t+2], c3=cnt[4*t+3];
  int s = c0+c1+c2+c3;
  sd[t] = s; __syncthreads();
  for (int off=1; off<1024; off<<=1){
    int v = (t>=off) ? sd[t-off] : 0;
    __syncthreads();
    sd[t] += v;
    __syncthreads();
  }
  int excl = sd[t]-s;
  ptr[4*t]=excl; ptr[4*t+1]=excl+c0; ptr[4*t+2]=excl+c0+c1; ptr[4*t+3]=excl+c0+c1+c2;
  if (t==1023) ptr[4096]=sd[1023];
}
// merged: block 0 -> dis; blocks 1..8 -> weight-fragment build (r17 table)
__global__ void k_misc(const int* __restrict__ deg, float* __restrict__ dis,
                       const float* __restrict__ x2hw, const float* __restrict__ h2hw,
                       const float* __restrict__ x2hb, const float* __restrict__ h2hb,
                       _Float16* __restrict__ wfrag){
  if (blockIdx.x == 0){
    #pragma unroll
    for (int k=0;k<4;++k){
      int n = threadIdx.x + k*1024;
      dis[n] = deg[n] > 0 ? rsqrtf((float)deg[n]) : 0.f;
    }
  } else {
    int i = (blockIdx.x-1)*1024 + threadIdx.x;     // 8192 total
    int f = i >> 9, lane = (i >> 3) & 63, j = i & 7;
    int kt = f >> 3, ct = f & 7;
    int k = kt*32 + (lane>>4)*8 + j;
    int col = ct*16 + (lane&15);
    float v;
    if (k < 12)       v = x2hw[k*128 + col];
    else if (k == 12) v = x2hb[col] + h2hb[col];
    else if (k < 32)  v = 0.f;
    else              v = h2hw[(k-32)*128 + col];
    wfrag[f*512 + lane*8 + j] = (_Float16)v;
  }
}
__global__ void k_fill(const int* __restrict__ ei, const float* __restrict__ dis,
                       const int* __restrict__ ptr, int* fillc, int2* __restrict__ epack){
  int e = blockIdx.x*blockDim.x + threadIdx.x;
  if (e < EC){
    int s = ei[e], d = ei[EC+e];
    int pos = ptr[d] + atomicAdd(&fillc[d],1);
    epack[pos] = make_int2(s, __float_as_int(-dis[s]*dis[d]));
  }
}

// ---------------- fused z + transpose: writes zT[n][slice] directly ----------
__global__ __launch_bounds__(256)
void k_zt(const float* __restrict__ pm25, const float* __restrict__ feat,
          const float* __restrict__ cw, f32x2* __restrict__ zT){
  __shared__ f32x2 tile[64][65];
  int nb = blockIdx.x & 63, sb = blockIdx.x >> 6;   // sb 0..11
  int n0 = nb*64, s0 = sb*64;
  int tid = threadIdx.x;
  #pragma unroll
  for (int k=0;k<16;++k){
    int i = tid + k*256;
    int r = i >> 6, c = i & 63;                     // r = slice off, c = node off
    int slice = s0 + r, n = n0 + c;
    int b = slice & 31;
    int t;
    float z0, z1;
    if (slice < 512){
      t = (slice >> 5) & 15;
      float x0 = pm25[((size_t)(b*HISTC + t))*Nn + n];
      z0 = x0*cw[20]; z1 = x0*cw[21];
    } else {
      t = HISTC + ((slice - 512) >> 5);
      z0 = 0.f; z1 = 0.f;
    }
    const float* fp = feat + ((size_t)(b*TTC + t)*Nn + n)*9;
    #pragma unroll
    for (int f=0;f<9;++f){
      float v = fp[f];
      z0 = fmaf(v, cw[20+(f+1)*2+0], z0); z1 = fmaf(v, cw[20+(f+1)*2+1], z1);
    }
    tile[r][c] = (f32x2){z0, z1};
  }
  __syncthreads();
  #pragma unroll
  for (int k=0;k<16;++k){
    int i = tid + k*256;
    int r = i >> 6, c = i & 63;                     // r = node off, c = slice off
    zT[(size_t)(n0 + r)*NSL + s0 + c] = tile[c][r];
  }
}

// ---------------- generic tiled transpose of f32x2 matrix [R][C] -> [C][R] ----
__global__ __launch_bounds__(256)
void k_tr(const f32x2* __restrict__ in, f32x2* __restrict__ out, int R, int C){
  __shared__ f32x2 tile[64][65];
  int tilesR = R >> 6;
  int br = blockIdx.x % tilesR, bc = blockIdx.x / tilesR;
  int r0 = br << 6, c0 = bc << 6;
  for (int i=threadIdx.x; i<4096; i+=256){
    int r = i>>6, c = i&63;
    tile[r][c] = in[(size_t)(r0+r)*C + c0+c];
  }
  __syncthreads();
  for (int i=threadIdx.x; i<4096; i+=256){
    int r = i>>6, c = i&63;
    out[(size_t)(c0+r)*R + r0+c] = tile[c][r];
  }
}

// ---------------- column-split dense agg: 6 passes of 64 float4 cols ----------
__global__ __launch_bounds__(64)
void k_aggc(const int* __restrict__ ptr, const int2* __restrict__ epack,
            const float4* __restrict__ zT, float4* __restrict__ aggT){
  int n  = blockIdx.x & (Nn-1);
  int cb = blockIdx.x >> 12;
  int col = cb*64 + threadIdx.x;              // float4 index in 384-wide row
  int p0 = ptr[n], p1 = ptr[n+1];
  f32x4 acc = {0.f,0.f,0.f,0.f};
  int i = p0;
  for (; i+1 < p1; i += 2){
    int2 e0 = epack[i], e1 = epack[i+1];
    float w0 = __int_as_float(e0.y), w1 = __int_as_float(e1.y);
    float4 z0 = zT[(size_t)e0.x*384 + col];
    float4 z1 = zT[(size_t)e1.x*384 + col];
    acc.x = fmaf(w0, z0.x, acc.x); acc.y = fmaf(w0, z0.y, acc.y);
    acc.z = fmaf(w0, z0.z, acc.z); acc.w = fmaf(w0, z0.w, acc.w);
    acc.x = fmaf(w1, z1.x, acc.x); acc.y = fmaf(w1, z1.y, acc.y);
    acc.z = fmaf(w1, z1.z, acc.z); acc.w = fmaf(w1, z1.w, acc.w);
  }
  if (i < p1){
    int2 e = epack[i];
    float w = __int_as_float(e.y);
    float4 z = zT[(size_t)e.x*384 + col];
    acc.x = fmaf(w, z.x, acc.x); acc.y = fmaf(w, z.y, acc.y);
    acc.z = fmaf(w, z.z, acc.z); acc.w = fmaf(w, z.w, acc.w);
  }
  aggT[(size_t)n*384 + col] = make_float4(acc.x, acc.y, acc.z, acc.w);
}

// ---------------- MFMA LSTM pointwise helper (proven) ----------------
#define POINTWISE(r)                                                            \
  c0[r] = fmaf(sigm_f(acc[0][r]), tanh_f(acc[4][r]), sigm_f(acc[2][r])*c0[r]);  \
  h0[r] = sigm_f(acc[6][r])*tanh_f(c0[r]);                                      \
  c1[r] = fmaf(sigm_f(acc[1][r]), tanh_f(acc[5][r]), sigm_f(acc[3][r])*c1[r]);  \
  h1[r] = sigm_f(acc[7][r])*tanh_f(c1[r]);

// ---------------- persistent history LSTM: packed 12KB weight LDS -------------
// wl0: kt=0 frags, lanes g4<2 only (upper k-slots are structurally zero)
__global__ __launch_bounds__(256,1)
void k_hist(const float* __restrict__ pm25, const float* __restrict__ feat,
            const f32x2* __restrict__ aggH,
            const float* __restrict__ cw, const float* __restrict__ cb,
            const uint4* __restrict__ wfrag,
            const float* __restrict__ fcw, const float* __restrict__ fcb,
            uint4* __restrict__ hfragO, uint4* __restrict__ cO,
            float* __restrict__ xn0){
  __shared__ __align__(16) uint4 wl0[256];          // 4 KB (kt=0, packed)
  __shared__ __align__(16) uint4 wl1[512];          // 8 KB (kt=1, full)
  __shared__ __align__(16) _Float16 hl[4][16][40];  // 5 KB
  int tid = threadIdx.x;
  int lane = tid & 63, w = tid >> 6;
  {
    int i = tid;                                    // 256 thr -> wl0 in one pass
    int ct = i >> 5, l32 = i & 31;
    wl0[i] = wfrag[ct*64 + l32];
    wl1[i]       = wfrag[512 + i];
    wl1[i + 256] = wfrag[768 + i];
  }
  int gw = blockIdx.x*4 + w;
  int r0 = gw*16;
  int b = r0 >> 12, n0 = r0 & (Nn-1);
  int l15 = lane & 15, g4 = lane >> 4;
  int nrow = n0 + l15;
  const float* pb = pm25 + (size_t)b*HISTC*Nn + nrow;
  const float* fb = feat + ((size_t)b*TTC*Nn + nrow)*9;

  float fw0 = fcw[l15], fw1 = fcw[l15+16];
  const f32x4 zacc = {0.f,0.f,0.f,0.f};

  uint4 ah = make_uint4(0,0,0,0);
  float c0[4]={0,0,0,0}, c1[4]={0,0,0,0};
  float h0[4], h1[4];
  bool upper = (g4 >= 2);
  __syncthreads();                                  // wl ready

  #pragma unroll 1
  for (int t=0; t<HISTC; ++t){
    int wofs = lane;
    asm volatile("" : "+v"(wofs));                  // opaque: prevent hoisting wl reads
    const float* fbt = fb + (size_t)t*Nn*9;
    float xv[9]; float a0 = 0.f, a1 = 0.f; float x0 = 0.f;
    if (g4 == 0){
      x0 = pb[(size_t)t*Nn];
      #pragma unroll
      for (int f=0;f<7;++f) xv[f] = fbt[f];
      a0 = x0*cw[0]; a1 = x0*cw[1];
      #pragma unroll
      for (int f=0;f<7;++f){ a0 += xv[f]*cw[(f+1)*2]; a1 += xv[f]*cw[(f+1)*2+1]; }
    } else if (g4 == 1){
      xv[7] = fbt[7]; xv[8] = fbt[8];
      a0 = cb[0] + xv[7]*cw[16] + xv[8]*cw[18];
      a1 = cb[1] + xv[7]*cw[17] + xv[8]*cw[19];
    } else if (g4 == 2){
      f32x2 ag = aggH[((size_t)(t*Bb + b))*Nn + nrow];
      a0 = ag.x; a1 = ag.y;
    }
    a0 += __shfl_xor(a0, 16); a0 += __shfl_xor(a0, 32);
    a1 += __shfl_xor(a1, 16); a1 += __shfl_xor(a1, 32);
    float xg0 = sigm_f(a0), xg1 = sigm_f(a1);

    uint4 ax;
    if (g4 == 0){
      ax.x = pk2(x0, xv[0]);     ax.y = pk2(xv[1], xv[2]);
      ax.z = pk2(xv[3], xv[4]);  ax.w = pk2(xv[5], xv[6]);
    } else if (g4 == 1){
      ax.x = pk2(xv[7], xv[8]);  ax.y = pk2(xg0, xg1);
      ax.z = pk2(1.f, 0.f);      ax.w = 0u;
    } else {
      ax = make_uint4(0,0,0,0);
    }

    f32x4 acc[8];
    #pragma unroll
    for (int ct=0; ct<8; ++ct){
      uint4 b0 = wl0[(wofs & 31) + ct*32];
      if (upper) b0 = make_uint4(0,0,0,0);          // structurally-zero k-slots
      uint4 b1 = wl1[wofs + ct*64];
      acc[ct] = mfma16(ax, b0, zacc);
      acc[ct] = mfma16(ah, b1, acc[ct]);
    }

    POINTWISE(0) POINTWISE(1) POINTWISE(2) POINTWISE(3)

    #pragma unroll
    for (int r=0;r<4;++r){
      hl[w][g4*4+r][l15]    = (_Float16)h0[r];
      hl[w][g4*4+r][l15+16] = (_Float16)h1[r];
    }
    asm volatile("s_waitcnt lgkmcnt(0)" ::: "memory");
    ah = *(const uint4*)&hl[w][l15][g4*8];
  }

  hfragO[(size_t)gw*64 + lane] = ah;
  {
    uint4 cp;
    cp.x = pk2(c0[0], c0[1]); cp.y = pk2(c0[2], c0[3]);
    cp.z = pk2(c1[0], c1[1]); cp.w = pk2(c1[2], c1[3]);
    cO[(size_t)gw*64 + lane] = cp;
  }
  #pragma unroll
  for (int r=0;r<4;++r){
    float p = fmaf(h0[r], fw0, h1[r]*fw1);
    p += __shfl_xor(p, 1, 16); p += __shfl_xor(p, 2, 16);
    p += __shfl_xor(p, 4, 16); p += __shfl_xor(p, 8, 16);
    if (l15 == 0) xn0[r0 + g4*4 + r] = p + fcb[0];
  }
}

// ---------------- pred step: packed weight LDS + in-kernel xn gather ----------
__global__ __launch_bounds__(256,1)
void k_pred_cell(const float* __restrict__ feat,
                 const float* __restrict__ xnI, float* __restrict__ xnO,
                 const f32x2* __restrict__ aggzf,     // pre-offset by (512+tp*32)*Nn
                 const int* __restrict__ ptr, const int2* __restrict__ epack,
                 const float* __restrict__ cw, const float* __restrict__ cb,
                 const uint4* __restrict__ wfrag,
                 const float* __restrict__ fcw, const float* __restrict__ fcb,
                 uint4* __restrict__ hfrag, uint4* __restrict__ cS,
                 float* __restrict__ out, int t){
  __shared__ __align__(16) uint4 wl0[256];
  __shared__ __align__(16) uint4 wl1[512];
  __shared__ __align__(16) _Float16 hl[4][16][40];
  int tid = threadIdx.x;
  int lane = tid & 63, w = tid >> 6;
  {
    int i = tid;
    int ct = i >> 5, l32 = i & 31;
    wl0[i] = wfrag[ct*64 + l32];
    wl1[i]       = wfrag[512 + i];
    wl1[i + 256] = wfrag[768 + i];
  }
  int gw = blockIdx.x*4 + w;
  int r0 = gw*16;
  int b = r0 >> 12, n0 = r0 & (Nn-1);
  int l15 = lane & 15, g4 = lane >> 4;
  int nrow = n0 + l15;
  bool upper = (g4 >= 2);

  float fw0 = fcw[l15], fw1 = fcw[l15+16];

  uint4 ah = hfrag[(size_t)gw*64 + lane];
  float c0[4], c1[4];
  {
    uint4 cv = cS[(size_t)gw*64 + lane];
    unpk2(cv.x, c0[0], c0[1]); unpk2(cv.y, c0[2], c0[3]);
    unpk2(cv.z, c1[0], c1[1]); unpk2(cv.w, c1[2], c1[3]);
  }
  float h0[4], h1[4];
  const f32x4 zacc = {0.f,0.f,0.f,0.f};

  const float* fbt = feat + ((size_t)(b*TTC + t)*Nn + nrow)*9;
  const float* xb = xnI + (size_t)b*Nn;
  float xv[9]; float a0 = 0.f, a1 = 0.f; float x0 = 0.f;
  if (g4 == 0){
    x0 = xb[nrow];
    #pragma unroll
    for (int f=0;f<7;++f) xv[f] = fbt[f];
    a0 = x0*cw[0]; a1 = x0*cw[1];
    #pragma unroll
    for (int f=0;f<7;++f){ a0 += xv[f]*cw[(f+1)*2]; a1 += xv[f]*cw[(f+1)*2+1]; }
  } else if (g4 == 1){
    xv[7] = fbt[7]; xv[8] = fbt[8];
    a0 = cb[0] + xv[7]*cw[16] + xv[8]*cw[18];
    a1 = cb[1] + xv[7]*cw[17] + xv[8]*cw[19];
  } else if (g4 == 2){
    f32x2 azf = aggzf[(size_t)b*Nn + nrow];
    a0 = azf.x; a1 = azf.y;
  }
  // in-wave xn sparse gather: 4 lanes (g4) split row nrow's CSR range
  {
    int p0 = ptr[nrow], p1 = ptr[nrow+1];
    float pax = 0.f;
    for (int i = p0 + g4; i < p1; i += 4){
      int2 e = epack[i];
      pax = fmaf(__int_as_float(e.y), xb[e.x], pax);
    }
    a0 = fmaf(pax, cw[20], a0);
    a1 = fmaf(pax, cw[21], a1);
  }
  a0 += __shfl_xor(a0, 16); a0 += __shfl_xor(a0, 32);
  a1 += __shfl_xor(a1, 16); a1 += __shfl_xor(a1, 32);
  float xg0 = sigm_f(a0), xg1 = sigm_f(a1);

  uint4 ax;
  if (g4 == 0){
    ax.x = pk2(x0, xv[0]);     ax.y = pk2(xv[1], xv[2]);
    ax.z = pk2(xv[3], xv[4]);  ax.w = pk2(xv[5], xv[6]);
  } else if (g4 == 1){
    ax.x = pk2(xv[7], xv[8]);  ax.y = pk2(xg0, xg1);
    ax.z = pk2(1.f, 0.f);      ax.w = 0u;
  } else {
    ax = make_uint4(0,0,0,0);
  }

  __syncthreads();                                  // wl ready
  f32x4 acc[8];
  #pragma unroll
  for (int ct=0; ct<8; ++ct){
    uint4 b0 = wl0[(lane & 31) + ct*32];
    if (upper) b0 = make_uint4(0,0,0,0);
    uint4 b1 = wl1[lane + ct*64];
    acc[ct] = mfma16(ax, b0, zacc);
    acc[ct] = mfma16(ah, b1, acc[ct]);
  }

  POINTWISE(0) POINTWISE(1) POINTWISE(2) POINTWISE(3)

  #pragma unroll
  for (int r=0;r<4;++r){
    hl[w][g4*4+r][l15]    = (_Float16)h0[r];
    hl[w][g4*4+r][l15+16] = (_Float16)h1[r];
  }
  asm volatile("s_waitcnt lgkmcnt(0)" ::: "memory");
  ah = *(const uint4*)&hl[w][l15][g4*8];

  hfrag[(size_t)gw*64 + lane] = ah;
  {
    uint4 cp;
    cp.x = pk2(c0[0], c0[1]); cp.y = pk2(c0[2], c0[3]);
    cp.z = pk2(c1[0], c1[1]); cp.w = pk2(c1[2], c1[3]);
    cS[(size_t)gw*64 + lane] = cp;
  }
  #pragma unroll
  for (int r=0;r<4;++r){
    float p = fmaf(h0[r], fw0, h1[r]*fw1);
    p += __shfl_xor(p, 1, 16); p += __shfl_xor(p, 2, 16);
    p += __shfl_xor(p, 4, 16); p += __shfl_xor(p, 8, 16);
    if (l15 == 0){
      float rr = p + fcb[0];
      int nr = n0 + g4*4 + r;
      xnO[r0 + g4*4 + r] = rr;
      out[(size_t)b*PREDC*Nn + nr] = rr;      // out pre-offset by tp*Nn
    }
  }
}

// ---------------- host ----------------
extern "C" void kernel_launch(void* const* d_in, const int* in_sizes, int n_in,
                              void* d_out, int out_size, void* d_ws, size_t ws_size,
                              hipStream_t stream){
  const float* pm25 = (const float*)d_in[0];
  const float* feat = (const float*)d_in[1];
  const int*   ei   = (const int*)d_in[2];
  const float* cw   = (const float*)d_in[3];
  const float* cb   = (const float*)d_in[4];
  const float* x2hw = (const float*)d_in[5];
  const float* x2hb = (const float*)d_in[6];
  const float* h2hw = (const float*)d_in[7];
  const float* h2hb = (const float*)d_in[8];
  const float* fcw  = (const float*)d_in[9];
  const float* fcb  = (const float*)d_in[10];
  float* out = (float*)d_out;

  char* wsp = (char*)d_ws;
  size_t off = 0;
  auto take = [&](size_t bytes)->char*{
    char* r = wsp + off; off += (bytes + 255) & ~(size_t)255; return r;
  };
  int*      deg   = (int*)      take(Nn*4);
  int*      cnt   = (int*)      take(Nn*4);
  int*      fillc = (int*)      take(Nn*4);
  int*      ptr   = (int*)      take((Nn+1)*4);
  float*    dis   = (float*)    take(Nn*4);
  int2*     epack = (int2*)     take(EC*8);
  _Float16* wfrag = (_Float16*) take(16*512*2);
  char*     bufA  =             take((size_t)NSL*Nn*8);   // aggT -> {hfrag,cbuf}
  char*     bufB  =             take((size_t)NSL*Nn*8);   // zT   -> aggAll
  float*    xn0   = (float*)    take((size_t)BN*4);
  float*    xn1   = (float*)    take((size_t)BN*4);

  uint4*  hfrag = (uint4*)bufA;                           // reuse after agg pipeline
  uint4*  cbuf  = (uint4*)(bufA + (size_t)8388608);       // f16-packed c state

  (void)hipMemsetAsync(deg, 0, Nn*4*3, stream);   // deg,cnt,fillc adjacent

  k_deg <<<EC/256, 256, 0, stream>>>(ei, deg, cnt);
  k_scan<<<1, 1024, 0, stream>>>(cnt, ptr);
  k_misc<<<9, 1024, 0, stream>>>(deg, dis, x2hw, h2hw, x2hb, h2hb, wfrag);
  k_fill<<<EC/256, 256, 0, stream>>>(ei, dis, ptr, fillc, epack);

  // dense agg pipeline: fused z+transpose -> dense agg -> transpose back
  k_zt<<<(NSL/64)*(Nn/64), 256, 0, stream>>>(pm25, feat, cw, (f32x2*)bufB);
  k_aggc<<<6*Nn, 64, 0, stream>>>(ptr, epack, (const float4*)bufB, (float4*)bufA);
  k_tr<<<(Nn/64)*(NSL/64), 256, 0, stream>>>((const f32x2*)bufA, (f32x2*)bufB, Nn, NSL);

  const f32x2* aggAll = (const f32x2*)bufB;     // [768][4096]

  k_hist<<<BN/64, 256, 0, stream>>>(pm25, feat, aggAll, cw, cb,
                                    (const uint4*)wfrag, fcw, fcb,
                                    hfrag, cbuf, xn0);

  for (int tp = 0; tp < PREDC; ++tp){
    int t = HISTC + tp;
    const float* xi = (tp & 1) ? xn1 : xn0;
    float*       xo = (tp & 1) ? xn0 : xn1;
    k_pred_cell<<<BN/64, 256, 0, stream>>>(feat, xi, xo,
                                           aggAll + (size_t)(512 + tp*Bb)*Nn,
                                           ptr, epack, cw, cb,
                                           (const uint4*)wfrag, fcw, fcb,
                                           hfrag, cbuf, out + (size_t)tp*Nn, t);
  }
}

// Round 22
// 369.055 us; speedup vs baseline: 1.0345x; 1.0044x over previous
//
#include <hip/hip_runtime.h>
#include <math.h>

#define Bb    32
#define Nn    4096
#define HISTC 16
#define PREDC 8
#define TTC   24
#define EC    65536
#define BN    (Bb*Nn)          // 131072
#define NSL   768              // 512 hist + 256 pred slices

typedef float f32x2 __attribute__((ext_vector_type(2)));
typedef float f32x4 __attribute__((ext_vector_type(4)));
typedef __fp16 f16x8 __attribute__((ext_vector_type(8)));
typedef __fp16 fp16v2 __attribute__((ext_vector_type(2)));

__device__ __forceinline__ float sigm_f(float x){
  return __builtin_amdgcn_rcpf(1.f + __expf(-x));
}
__device__ __forceinline__ float tanh_f(float x){
  return fmaf(-2.f, __builtin_amdgcn_rcpf(1.f + __expf(2.f*x)), 1.f);
}
__device__ __forceinline__ unsigned pk2(float a, float b){
  fp16v2 v = __builtin_amdgcn_cvt_pkrtz(a, b);
  return __builtin_bit_cast(unsigned, v);
}
__device__ __forceinline__ void unpk2(unsigned u, float& a, float& b){
  fp16v2 v = __builtin_bit_cast(fp16v2, u);
  a = (float)v.x; b = (float)v.y;
}
__device__ __forceinline__ f32x4 mfma16(uint4 a, uint4 b, f32x4 c){
  return __builtin_amdgcn_mfma_f32_16x16x32_f16(
      __builtin_bit_cast(f16x8, a), __builtin_bit_cast(f16x8, b), c, 0, 0, 0);
}

// ---------------- CSR build ----------------
__global__ void k_deg(const int* __restrict__ ei, int* deg, int* cnt){
  int e = blockIdx.x*blockDim.x + threadIdx.x;
  if (e < EC){ atomicAdd(&deg[ei[e]],1); atomicAdd(&cnt[ei[EC+e]],1); }
}
__global__ void k_scan(const int* __restrict__ cnt, int* ptr){
  __shared__ int sd[1024];
  int t = threadIdx.x;
  int c0=cnt[4*t], c1=cnt[4*t+1], c2=cnt[4*t+2], c3=cnt[4*t+3];
  int s = c0+c1+c2+c3;
  sd[t] = s; __syncthreads();
  for (int off=1; off<1024; off<<=1){
    int v = (t>=off) ? sd[t-off] : 0;
    __syncthreads();
    sd[t] += v;
    __syncthreads();
  }
  int excl = sd[t]-s;
  ptr[4*t]=excl; ptr[4*t+1]=excl+c0; ptr[4*t+2]=excl+c0+c1; ptr[4*t+3]=excl+c0+c1+c2;
  if (t==1023) ptr[4096]=sd[1023];
}
// merged: block 0 -> dis; blocks 1..8 -> weight-fragment build (r17 table)
__global__ void k_misc(const int* __restrict__ deg, float* __restrict__ dis,
                       const float* __restrict__ x2hw, const float* __restrict__ h2hw,
                       const float* __restrict__ x2hb, const float* __restrict__ h2hb,
                       _Float16* __restrict__ wfrag){
  if (blockIdx.x == 0){
    #pragma unroll
    for (int k=0;k<4;++k){
      int n = threadIdx.x + k*1024;
      dis[n] = deg[n] > 0 ? rsqrtf((float)deg[n]) : 0.f;
    }
  } else {
    int i = (blockIdx.x-1)*1024 + threadIdx.x;     // 8192 total
    int f = i >> 9, lane = (i >> 3) & 63, j = i & 7;
    int kt = f >> 3, ct = f & 7;
    int k = kt*32 + (lane>>4)*8 + j;
    int col = ct*16 + (lane&15);
    float v;
    if (k < 12)       v = x2hw[k*128 + col];
    else if (k == 12) v = x2hb[col] + h2hb[col];
    else if (k < 32)  v = 0.f;
    else              v = h2hw[(k-32)*128 + col];
    wfrag[f*512 + lane*8 + j] = (_Float16)v;
  }
}
__global__ void k_fill(const int* __restrict__ ei, const float* __restrict__ dis,
                       const int* __restrict__ ptr, int* fillc, int2* __restrict__ epack){
  int e = blockIdx.x*blockDim.x + threadIdx.x;
  if (e < EC){
    int s = ei[e], d = ei[EC+e];
    int pos = ptr[d] + atomicAdd(&fillc[d],1);
    epack[pos] = make_int2(s, __float_as_int(-dis[s]*dis[d]));
  }
}

// ---------------- fused z + transpose: writes zT[n][slice] directly ----------
__global__ __launch_bounds__(256)
void k_zt(const float* __restrict__ pm25, const float* __restrict__ feat,
          const float* __restrict__ cw, f32x2* __restrict__ zT){
  __shared__ f32x2 tile[64][65];
  int nb = blockIdx.x & 63, sb = blockIdx.x >> 6;   // sb 0..11
  int n0 = nb*64, s0 = sb*64;
  int tid = threadIdx.x;
  #pragma unroll
  for (int k=0;k<16;++k){
    int i = tid + k*256;
    int r = i >> 6, c = i & 63;                     // r = slice off, c = node off
    int slice = s0 + r, n = n0 + c;
    int b = slice & 31;
    int t;
    float z0, z1;
    if (slice < 512){
      t = (slice >> 5) & 15;
      float x0 = pm25[((size_t)(b*HISTC + t))*Nn + n];
      z0 = x0*cw[20]; z1 = x0*cw[21];
    } else {
      t = HISTC + ((slice - 512) >> 5);
      z0 = 0.f; z1 = 0.f;
    }
    const float* fp = feat + ((size_t)(b*TTC + t)*Nn + n)*9;
    #pragma unroll
    for (int f=0;f<9;++f){
      float v = fp[f];
      z0 = fmaf(v, cw[20+(f+1)*2+0], z0); z1 = fmaf(v, cw[20+(f+1)*2+1], z1);
    }
    tile[r][c] = (f32x2){z0, z1};
  }
  __syncthreads();
  #pragma unroll
  for (int k=0;k<16;++k){
    int i = tid + k*256;
    int r = i >> 6, c = i & 63;                     // r = node off, c = slice off
    zT[(size_t)(n0 + r)*NSL + s0 + c] = tile[c][r];
  }
}

// ---------------- generic tiled transpose of f32x2 matrix [R][C] -> [C][R] ----
__global__ __launch_bounds__(256)
void k_tr(const f32x2* __restrict__ in, f32x2* __restrict__ out, int R, int C){
  __shared__ f32x2 tile[64][65];
  int tilesR = R >> 6;
  int br = blockIdx.x % tilesR, bc = blockIdx.x / tilesR;
  int r0 = br << 6, c0 = bc << 6;
  for (int i=threadIdx.x; i<4096; i+=256){
    int r = i>>6, c = i&63;
    tile[r][c] = in[(size_t)(r0+r)*C + c0+c];
  }
  __syncthreads();
  for (int i=threadIdx.x; i<4096; i+=256){
    int r = i>>6, c = i&63;
    out[(size_t)(c0+r)*R + r0+c] = tile[c][r];
  }
}

// ---------------- column-split dense agg: 6 passes of 64 float4 cols ----------
__global__ __launch_bounds__(64)
void k_aggc(const int* __restrict__ ptr, const int2* __restrict__ epack,
            const float4* __restrict__ zT, float4* __restrict__ aggT){
  int n  = blockIdx.x & (Nn-1);
  int cb = blockIdx.x >> 12;
  int col = cb*64 + threadIdx.x;              // float4 index in 384-wide row
  int p0 = ptr[n], p1 = ptr[n+1];
  f32x4 acc = {0.f,0.f,0.f,0.f};
  int i = p0;
  for (; i+1 < p1; i += 2){
    int2 e0 = epack[i], e1 = epack[i+1];
    float w0 = __int_as_float(e0.y), w1 = __int_as_float(e1.y);
    float4 z0 = zT[(size_t)e0.x*384 + col];
    float4 z1 = zT[(size_t)e1.x*384 + col];
    acc.x = fmaf(w0, z0.x, acc.x); acc.y = fmaf(w0, z0.y, acc.y);
    acc.z = fmaf(w0, z0.z, acc.z); acc.w = fmaf(w0, z0.w, acc.w);
    acc.x = fmaf(w1, z1.x, acc.x); acc.y = fmaf(w1, z1.y, acc.y);
    acc.z = fmaf(w1, z1.z, acc.z); acc.w = fmaf(w1, z1.w, acc.w);
  }
  if (i < p1){
    int2 e = epack[i];
    float w = __int_as_float(e.y);
    float4 z = zT[(size_t)e.x*384 + col];
    acc.x = fmaf(w, z.x, acc.x); acc.y = fmaf(w, z.y, acc.y);
    acc.z = fmaf(w, z.z, acc.z); acc.w = fmaf(w, z.w, acc.w);
  }
  aggT[(size_t)n*384 + col] = make_float4(acc.x, acc.y, acc.z, acc.w);
}

// ---------------- MFMA LSTM pointwise helper (proven) ----------------
#define POINTWISE(r)                                                            \
  c0[r] = fmaf(sigm_f(acc[0][r]), tanh_f(acc[4][r]), sigm_f(acc[2][r])*c0[r]);  \
  h0[r] = sigm_f(acc[6][r])*tanh_f(c0[r]);                                      \
  c1[r] = fmaf(sigm_f(acc[1][r]), tanh_f(acc[5][r]), sigm_f(acc[3][r])*c1[r]);  \
  h1[r] = sigm_f(acc[7][r])*tanh_f(c1[r]);

// ---------------- persistent history LSTM (r17 proven: full 16KB wl) ----------
__global__ __launch_bounds__(256,1)
void k_hist(const float* __restrict__ pm25, const float* __restrict__ feat,
            const f32x2* __restrict__ aggH,
            const float* __restrict__ cw, const float* __restrict__ cb,
            const uint4* __restrict__ wfrag,
            const float* __restrict__ fcw, const float* __restrict__ fcb,
            uint4* __restrict__ hfragO, uint4* __restrict__ cO,
            float* __restrict__ xn0){
  __shared__ __align__(16) uint4 wl[1024];          // 16 KB weight fragments
  __shared__ __align__(16) _Float16 hl[4][16][40];
  int tid = threadIdx.x;
  int lane = tid & 63, w = tid >> 6;
  for (int i = tid; i < 1024; i += 256) wl[i] = wfrag[i];
  int gw = blockIdx.x*4 + w;
  int r0 = gw*16;
  int b = r0 >> 12, n0 = r0 & (Nn-1);
  int l15 = lane & 15, g4 = lane >> 4;
  int nrow = n0 + l15;
  const float* pb = pm25 + (size_t)b*HISTC*Nn + nrow;
  const float* fb = feat + ((size_t)b*TTC*Nn + nrow)*9;

  float fw0 = fcw[l15], fw1 = fcw[l15+16];
  const f32x4 zacc = {0.f,0.f,0.f,0.f};

  uint4 ah = make_uint4(0,0,0,0);
  float c0[4]={0,0,0,0}, c1[4]={0,0,0,0};
  float h0[4], h1[4];
  __syncthreads();                                  // wl ready

  #pragma unroll 1
  for (int t=0; t<HISTC; ++t){
    int wofs = lane;
    asm volatile("" : "+v"(wofs));                  // opaque: prevent hoisting wl reads
    const float* fbt = fb + (size_t)t*Nn*9;
    float xv[9]; float a0 = 0.f, a1 = 0.f; float x0 = 0.f;
    if (g4 == 0){
      x0 = pb[(size_t)t*Nn];
      #pragma unroll
      for (int f=0;f<7;++f) xv[f] = fbt[f];
      a0 = x0*cw[0]; a1 = x0*cw[1];
      #pragma unroll
      for (int f=0;f<7;++f){ a0 += xv[f]*cw[(f+1)*2]; a1 += xv[f]*cw[(f+1)*2+1]; }
    } else if (g4 == 1){
      xv[7] = fbt[7]; xv[8] = fbt[8];
      a0 = cb[0] + xv[7]*cw[16] + xv[8]*cw[18];
      a1 = cb[1] + xv[7]*cw[17] + xv[8]*cw[19];
    } else if (g4 == 2){
      f32x2 ag = aggH[((size_t)(t*Bb + b))*Nn + nrow];
      a0 = ag.x; a1 = ag.y;
    }
    a0 += __shfl_xor(a0, 16); a0 += __shfl_xor(a0, 32);
    a1 += __shfl_xor(a1, 16); a1 += __shfl_xor(a1, 32);
    float xg0 = sigm_f(a0), xg1 = sigm_f(a1);

    uint4 ax;
    if (g4 == 0){
      ax.x = pk2(x0, xv[0]);     ax.y = pk2(xv[1], xv[2]);
      ax.z = pk2(xv[3], xv[4]);  ax.w = pk2(xv[5], xv[6]);
    } else if (g4 == 1){
      ax.x = pk2(xv[7], xv[8]);  ax.y = pk2(xg0, xg1);
      ax.z = pk2(1.f, 0.f);      ax.w = 0u;
    } else {
      ax = make_uint4(0,0,0,0);
    }

    f32x4 acc[8];
    #pragma unroll
    for (int ct=0; ct<8; ++ct){
      uint4 b0 = wl[wofs + ct*64];
      uint4 b1 = wl[wofs + 512 + ct*64];
      acc[ct] = mfma16(ax, b0, zacc);
      acc[ct] = mfma16(ah, b1, acc[ct]);
    }

    POINTWISE(0) POINTWISE(1) POINTWISE(2) POINTWISE(3)

    #pragma unroll
    for (int r=0;r<4;++r){
      hl[w][g4*4+r][l15]    = (_Float16)h0[r];
      hl[w][g4*4+r][l15+16] = (_Float16)h1[r];
    }
    asm volatile("s_waitcnt lgkmcnt(0)" ::: "memory");
    ah = *(const uint4*)&hl[w][l15][g4*8];
  }

  hfragO[(size_t)gw*64 + lane] = ah;
  {
    uint4 cp;
    cp.x = pk2(c0[0], c0[1]); cp.y = pk2(c0[2], c0[3]);
    cp.z = pk2(c1[0], c1[1]); cp.w = pk2(c1[2], c1[3]);
    cO[(size_t)gw*64 + lane] = cp;
  }
  #pragma unroll
  for (int r=0;r<4;++r){
    float p = fmaf(h0[r], fw0, h1[r]*fw1);
    p += __shfl_xor(p, 1, 16); p += __shfl_xor(p, 2, 16);
    p += __shfl_xor(p, 4, 16); p += __shfl_xor(p, 8, 16);
    if (l15 == 0) xn0[r0 + g4*4 + r] = p + fcb[0];
  }
}

// ---------------- pred step (r21 proven: packed 12KB weight LDS) --------------
__global__ __launch_bounds__(256,1)
void k_pred_cell(const float* __restrict__ feat,
                 const float* __restrict__ xnI, float* __restrict__ xnO,
                 const f32x2* __restrict__ aggzf,     // pre-offset by (512+tp*32)*Nn
                 const int* __restrict__ ptr, const int2* __restrict__ epack,
                 const float* __restrict__ cw, const float* __restrict__ cb,
                 const uint4* __restrict__ wfrag,
                 const float* __restrict__ fcw, const float* __restrict__ fcb,
                 uint4* __restrict__ hfrag, uint4* __restrict__ cS,
                 float* __restrict__ out, int t){
  __shared__ __align__(16) uint4 wl0[256];
  __shared__ __align__(16) uint4 wl1[512];
  __shared__ __align__(16) _Float16 hl[4][16][40];
  int tid = threadIdx.x;
  int lane = tid & 63, w = tid >> 6;
  {
    int i = tid;
    int ct = i >> 5, l32 = i & 31;
    wl0[i] = wfrag[ct*64 + l32];
    wl1[i]       = wfrag[512 + i];
    wl1[i + 256] = wfrag[768 + i];
  }
  int gw = blockIdx.x*4 + w;
  int r0 = gw*16;
  int b = r0 >> 12, n0 = r0 & (Nn-1);
  int l15 = lane & 15, g4 = lane >> 4;
  int nrow = n0 + l15;
  bool upper = (g4 >= 2);

  float fw0 = fcw[l15], fw1 = fcw[l15+16];

  uint4 ah = hfrag[(size_t)gw*64 + lane];
  float c0[4], c1[4];
  {
    uint4 cv = cS[(size_t)gw*64 + lane];
    unpk2(cv.x, c0[0], c0[1]); unpk2(cv.y, c0[2], c0[3]);
    unpk2(cv.z, c1[0], c1[1]); unpk2(cv.w, c1[2], c1[3]);
  }
  float h0[4], h1[4];
  const f32x4 zacc = {0.f,0.f,0.f,0.f};

  const float* fbt = feat + ((size_t)(b*TTC + t)*Nn + nrow)*9;
  const float* xb = xnI + (size_t)b*Nn;
  float xv[9]; float a0 = 0.f, a1 = 0.f; float x0 = 0.f;
  if (g4 == 0){
    x0 = xb[nrow];
    #pragma unroll
    for (int f=0;f<7;++f) xv[f] = fbt[f];
    a0 = x0*cw[0]; a1 = x0*cw[1];
    #pragma unroll
    for (int f=0;f<7;++f){ a0 += xv[f]*cw[(f+1)*2]; a1 += xv[f]*cw[(f+1)*2+1]; }
  } else if (g4 == 1){
    xv[7] = fbt[7]; xv[8] = fbt[8];
    a0 = cb[0] + xv[7]*cw[16] + xv[8]*cw[18];
    a1 = cb[1] + xv[7]*cw[17] + xv[8]*cw[19];
  } else if (g4 == 2){
    f32x2 azf = aggzf[(size_t)b*Nn + nrow];
    a0 = azf.x; a1 = azf.y;
  }
  // in-wave xn sparse gather: 4 lanes (g4) split row nrow's CSR range
  {
    int p0 = ptr[nrow], p1 = ptr[nrow+1];
    float pax = 0.f;
    for (int i = p0 + g4; i < p1; i += 4){
      int2 e = epack[i];
      pax = fmaf(__int_as_float(e.y), xb[e.x], pax);
    }
    a0 = fmaf(pax, cw[20], a0);
    a1 = fmaf(pax, cw[21], a1);
  }
  a0 += __shfl_xor(a0, 16); a0 += __shfl_xor(a0, 32);
  a1 += __shfl_xor(a1, 16); a1 += __shfl_xor(a1, 32);
  float xg0 = sigm_f(a0), xg1 = sigm_f(a1);

  uint4 ax;
  if (g4 == 0){
    ax.x = pk2(x0, xv[0]);     ax.y = pk2(xv[1], xv[2]);
    ax.z = pk2(xv[3], xv[4]);  ax.w = pk2(xv[5], xv[6]);
  } else if (g4 == 1){
    ax.x = pk2(xv[7], xv[8]);  ax.y = pk2(xg0, xg1);
    ax.z = pk2(1.f, 0.f);      ax.w = 0u;
  } else {
    ax = make_uint4(0,0,0,0);
  }

  __syncthreads();                                  // wl ready
  f32x4 acc[8];
  #pragma unroll
  for (int ct=0; ct<8; ++ct){
    uint4 b0 = wl0[(lane & 31) + ct*32];
    if (upper) b0 = make_uint4(0,0,0,0);
    uint4 b1 = wl1[lane + ct*64];
    acc[ct] = mfma16(ax, b0, zacc);
    acc[ct] = mfma16(ah, b1, acc[ct]);
  }

  POINTWISE(0) POINTWISE(1) POINTWISE(2) POINTWISE(3)

  #pragma unroll
  for (int r=0;r<4;++r){
    hl[w][g4*4+r][l15]    = (_Float16)h0[r];
    hl[w][g4*4+r][l15+16] = (_Float16)h1[r];
  }
  asm volatile("s_waitcnt lgkmcnt(0)" ::: "memory");
  ah = *(const uint4*)&hl[w][l15][g4*8];

  hfrag[(size_t)gw*64 + lane] = ah;
  {
    uint4 cp;
    cp.x = pk2(c0[0], c0[1]); cp.y = pk2(c0[2], c0[3]);
    cp.z = pk2(c1[0], c1[1]); cp.w = pk2(c1[2], c1[3]);
    cS[(size_t)gw*64 + lane] = cp;
  }
  #pragma unroll
  for (int r=0;r<4;++r){
    float p = fmaf(h0[r], fw0, h1[r]*fw1);
    p += __shfl_xor(p, 1, 16); p += __shfl_xor(p, 2, 16);
    p += __shfl_xor(p, 4, 16); p += __shfl_xor(p, 8, 16);
    if (l15 == 0){
      float rr = p + fcb[0];
      int nr = n0 + g4*4 + r;
      xnO[r0 + g4*4 + r] = rr;
      out[(size_t)b*PREDC*Nn + nr] = rr;      // out pre-offset by tp*Nn
    }
  }
}

// ---------------- host ----------------
extern "C" void kernel_launch(void* const* d_in, const int* in_sizes, int n_in,
                              void* d_out, int out_size, void* d_ws, size_t ws_size,
                              hipStream_t stream){
  const float* pm25 = (const float*)d_in[0];
  const float* feat = (const float*)d_in[1];
  const int*   ei   = (const int*)d_in[2];
  const float* cw   = (const float*)d_in[3];
  const float* cb   = (const float*)d_in[4];
  const float* x2hw = (const float*)d_in[5];
  const float* x2hb = (const float*)d_in[6];
  const float* h2hw = (const float*)d_in[7];
  const float* h2hb = (const float*)d_in[8];
  const float* fcw  = (const float*)d_in[9];
  const float* fcb  = (const float*)d_in[10];
  float* out = (float*)d_out;

  char* wsp = (char*)d_ws;
  size_t off = 0;
  auto take = [&](size_t bytes)->char*{
    char* r = wsp + off; off += (bytes + 255) & ~(size_t)255; return r;
  };
  int*      deg   = (int*)      take(Nn*4);
  int*      cnt   = (int*)      take(Nn*4);
  int*      fillc = (int*)      take(Nn*4);
  int*      ptr   = (int*)      take((Nn+1)*4);
  float*    dis   = (float*)    take(Nn*4);
  int2*     epack = (int2*)     take(EC*8);
  _Float16* wfrag = (_Float16*) take(16*512*2);
  char*     bufA  =             take((size_t)NSL*Nn*8);   // aggT -> {hfrag,cbuf}
  char*     bufB  =             take((size_t)NSL*Nn*8);   // zT   -> aggAll
  float*    xn0   = (float*)    take((size_t)BN*4);
  float*    xn1   = (float*)    take((size_t)BN*4);

  uint4*  hfrag = (uint4*)bufA;                           // reuse after agg pipeline
  uint4*  cbuf  = (uint4*)(bufA + (size_t)8388608);       // f16-packed c state

  (void)hipMemsetAsync(deg, 0, Nn*4*3, stream);   // deg,cnt,fillc adjacent

  k_deg <<<EC/256, 256, 0, stream>>>(ei, deg, cnt);
  k_scan<<<1, 1024, 0, stream>>>(cnt, ptr);
  k_misc<<<9, 1024, 0, stream>>>(deg, dis, x2hw, h2hw, x2hb, h2hb, wfrag);
  k_fill<<<EC/256, 256, 0, stream>>>(ei, dis, ptr, fillc, epack);

  // dense agg pipeline: fused z+transpose -> dense agg -> transpose back
  k_zt<<<(NSL/64)*(Nn/64), 256, 0, stream>>>(pm25, feat, cw, (f32x2*)bufB);
  k_aggc<<<6*Nn, 64, 0, stream>>>(ptr, epack, (const float4*)bufB, (float4*)bufA);
  k_tr<<<(Nn/64)*(NSL/64), 256, 0, stream>>>((const f32x2*)bufA, (f32x2*)bufB, Nn, NSL);

  const f32x2* aggAll = (const f32x2*)bufB;     // [768][4096]

  k_hist<<<BN/64, 256, 0, stream>>>(pm25, feat, aggAll, cw, cb,
                                    (const uint4*)wfrag, fcw, fcb,
                                    hfrag, cbuf, xn0);

  for (int tp = 0; tp < PREDC; ++tp){
    int t = HISTC + tp;
    const float* xi = (tp & 1) ? xn1 : xn0;
    float*       xo = (tp & 1) ? xn0 : xn1;
    k_pred_cell<<<BN/64, 256, 0, stream>>>(feat, xi, xo,
                                           aggAll + (size_t)(512 + tp*Bb)*Nn,
                                           ptr, epack, cw, cb,
                                           (const uint4*)wfrag, fcw, fcb,
                                           hfrag, cbuf, out + (size_t)tp*Nn, t);
  }
}